// Round 1
// baseline (359.141 us; speedup 1.0000x reference)
//
#include <hip/hip_runtime.h>
#include <hip/hip_bf16.h>
#include <math.h>

#define DIM 768
#define NH 12
#define DH 64
#define SEQ 2048
#define BATCH 2
#define TOK (BATCH*SEQ)   // 4096
#define QKVN (3*DIM)      // 2304

typedef __attribute__((ext_vector_type(8))) short bf16x8;
typedef __attribute__((ext_vector_type(4))) float f32x4;
typedef unsigned short u16;

__device__ inline u16 f2bf(float f) {
  union { float f; unsigned u; } v; v.f = f;
  unsigned u = v.u;
  u += 0x7fffu + ((u >> 16) & 1u);   // round-to-nearest-even
  return (u16)(u >> 16);
}

__global__ void conv_f2b(const float* __restrict__ in, u16* __restrict__ out, int n) {
  int i = blockIdx.x * blockDim.x + threadIdx.x;
  if (i < n) out[i] = f2bf(in[i]);
}

// C[M][Nn] = A[M][K] * W[Nn][K]^T (+bias), bf16 inputs, fp32 out.
// Block: 64(M) x 64(N), 4 waves each own 16 rows. Frags loaded direct from global.
__global__ __launch_bounds__(256) void gemm_bt(
    const u16* __restrict__ A, const u16* __restrict__ W,
    float* __restrict__ C, const float* __restrict__ bias,
    int M, int Nn, int K)
{
  const int w = threadIdx.x >> 6, l = threadIdx.x & 63;
  const int lr = l & 15, lg = l >> 4;
  const int m0 = blockIdx.x * 64 + w * 16;
  const int n0 = blockIdx.y * 64;
  f32x4 acc[4] = {};
  const u16* ap = A + (size_t)(m0 + lr) * K + 8 * lg;
  const u16* bp = W + (size_t)(n0 + lr) * K + 8 * lg;
  for (int k0 = 0; k0 < K; k0 += 32) {
    bf16x8 a = *(const bf16x8*)(ap + k0);
#pragma unroll
    for (int c = 0; c < 4; ++c) {
      bf16x8 b = *(const bf16x8*)(bp + (size_t)c * 16 * K + k0);
      acc[c] = __builtin_amdgcn_mfma_f32_16x16x32_bf16(a, b, acc[c], 0, 0, 0);
    }
  }
#pragma unroll
  for (int c = 0; c < 4; ++c) {
#pragma unroll
    for (int r = 0; r < 4; ++r) {
      int row = m0 + lg * 4 + r;
      int col = n0 + c * 16 + lr;
      float v = acc[c][r];
      if (bias) v += bias[col];
      C[(size_t)row * Nn + col] = v;
    }
  }
}

// Per token: RMSNorm(q,k) per head + RoPE, emit Q,K as (B,H,N,DH) bf16 and V
// transposed as (B,H,DH,N) bf16. One wave handles one head (lane = d).
__global__ __launch_bounds__(256) void postproc(
    const float* __restrict__ qkv, const float* __restrict__ pos,
    const float* __restrict__ qn_w, const float* __restrict__ kn_w,
    u16* __restrict__ Qb, u16* __restrict__ Kb, u16* __restrict__ Vtb)
{
  const int t = blockIdx.x;            // token 0..4095
  const int w = threadIdx.x >> 6;      // wave 0..3
  const int d = threadIdx.x & 63;
  const int b = t >> 11, n = t & 2047;
  // RoPE per-lane constants: pair p = d/2, angle index j = p, axis = p/10, fi = p%10
  float cs = 1.f, sn = 0.f;
  if (d < 60) {
    const int p = d >> 1;
    const int axis = p / 10, fi = p % 10;
    float freq = exp2f(-(float)fi * 1.3287712379549449f); // log2(10000)/10
    float ang = pos[t * 3 + axis] * freq;
    cs = cosf(ang); sn = sinf(ang);
  }
  const float qw = qn_w[d], kw = kn_w[d];
  for (int hh = 0; hh < 3; ++hh) {
    const int h = w + hh * 4;
    const float* base = qkv + (size_t)t * QKVN + h * DH + d;
    float q = base[0], k = base[DIM], v = base[2 * DIM];
    float sq = q * q, sk = k * k;
#pragma unroll
    for (int off = 32; off >= 1; off >>= 1) {
      sq += __shfl_xor(sq, off, 64);
      sk += __shfl_xor(sk, off, 64);
    }
    float qn = q * rsqrtf(sq * (1.f / 64.f) + 1e-6f) * qw;
    float kn = k * rsqrtf(sk * (1.f / 64.f) + 1e-6f) * kw;
    float qo = __shfl_xor(qn, 1, 64);
    float ko = __shfl_xor(kn, 1, 64);
    float qr = qn, kr = kn;
    if (d < 60) {
      if (d & 1) { qr = qo * sn + qn * cs; kr = ko * sn + kn * cs; }
      else       { qr = qn * cs - qo * sn; kr = kn * cs - ko * sn; }
    }
    const size_t bh = (size_t)(b * NH + h);
    Qb[(bh * SEQ + n) * DH + d] = f2bf(qr);
    Kb[(bh * SEQ + n) * DH + d] = f2bf(kr);
    Vtb[(bh * DH + d) * SEQ + n] = f2bf(v);
  }
}

// Flash attention. Grid (B*H, N/64). 4 waves, each owns 16 Q rows.
#define NPAD 72
__global__ __launch_bounds__(256) void attn(
    const u16* __restrict__ Qb, const u16* __restrict__ Kb,
    const u16* __restrict__ Vtb, u16* __restrict__ Ob)
{
  __shared__ u16 Ks[64][NPAD];
  __shared__ u16 Vs[64][NPAD];   // Vs[d][kk]
  __shared__ u16 Ps[4][16][NPAD];
  const int w = threadIdx.x >> 6, l = threadIdx.x & 63;
  const int lr = l & 15, lg = l >> 4;
  const int bh = blockIdx.x;
  const int q0 = blockIdx.y * 64;
  const u16* Qp = Qb + (size_t)bh * SEQ * DH;
  const u16* Kp = Kb + (size_t)bh * SEQ * DH;
  const u16* Vp = Vtb + (size_t)bh * DH * SEQ;
  const int qr = q0 + w * 16 + lr;
  const bf16x8 aq0 = *(const bf16x8*)(Qp + qr * DH + 8 * lg);
  const bf16x8 aq1 = *(const bf16x8*)(Qp + qr * DH + 32 + 8 * lg);
  float mrow[4], lsum[4];
  f32x4 oacc[4] = {};
#pragma unroll
  for (int r = 0; r < 4; ++r) { mrow[r] = -1e30f; lsum[r] = 0.f; }
  const int srow = threadIdx.x >> 2;          // 0..63
  const int scol = (threadIdx.x & 3) * 16;    // 0,16,32,48
  for (int kt = 0; kt < 32; ++kt) {
    const int kk0 = kt * 64;
    __syncthreads();
    *(bf16x8*)&Ks[srow][scol]     = *(const bf16x8*)(Kp + (size_t)(kk0 + srow) * DH + scol);
    *(bf16x8*)&Ks[srow][scol + 8] = *(const bf16x8*)(Kp + (size_t)(kk0 + srow) * DH + scol + 8);
    *(bf16x8*)&Vs[srow][scol]     = *(const bf16x8*)(Vp + (size_t)srow * SEQ + kk0 + scol);
    *(bf16x8*)&Vs[srow][scol + 8] = *(const bf16x8*)(Vp + (size_t)srow * SEQ + kk0 + scol + 8);
    __syncthreads();
    f32x4 s[4] = {};
#pragma unroll
    for (int c = 0; c < 4; ++c) {
      bf16x8 bk0 = *(const bf16x8*)&Ks[c * 16 + lr][8 * lg];
      bf16x8 bk1 = *(const bf16x8*)&Ks[c * 16 + lr][32 + 8 * lg];
      s[c] = __builtin_amdgcn_mfma_f32_16x16x32_bf16(aq0, bk0, s[c], 0, 0, 0);
      s[c] = __builtin_amdgcn_mfma_f32_16x16x32_bf16(aq1, bk1, s[c], 0, 0, 0);
    }
#pragma unroll
    for (int r = 0; r < 4; ++r) {
      float s0 = s[0][r] * 0.125f, s1 = s[1][r] * 0.125f;
      float s2 = s[2][r] * 0.125f, s3 = s[3][r] * 0.125f;
      float mx = fmaxf(fmaxf(s0, s1), fmaxf(s2, s3));
      mx = fmaxf(mx, __shfl_xor(mx, 1, 64));
      mx = fmaxf(mx, __shfl_xor(mx, 2, 64));
      mx = fmaxf(mx, __shfl_xor(mx, 4, 64));
      mx = fmaxf(mx, __shfl_xor(mx, 8, 64));
      float mnew = fmaxf(mrow[r], mx);
      float fsc = expf(mrow[r] - mnew);
      mrow[r] = mnew;
      float p0 = expf(s0 - mnew), p1 = expf(s1 - mnew);
      float p2 = expf(s2 - mnew), p3 = expf(s3 - mnew);
      const int prow = lg * 4 + r;
      Ps[w][prow][0 + lr]  = f2bf(p0);
      Ps[w][prow][16 + lr] = f2bf(p1);
      Ps[w][prow][32 + lr] = f2bf(p2);
      Ps[w][prow][48 + lr] = f2bf(p3);
      float psum = p0 + p1 + p2 + p3;
      psum += __shfl_xor(psum, 1, 64);
      psum += __shfl_xor(psum, 2, 64);
      psum += __shfl_xor(psum, 4, 64);
      psum += __shfl_xor(psum, 8, 64);
      lsum[r] = lsum[r] * fsc + psum;
#pragma unroll
      for (int dt = 0; dt < 4; ++dt) oacc[dt][r] *= fsc;
    }
    __syncthreads();   // make Ps visible (cross-lane via LDS)
#pragma unroll
    for (int g = 0; g < 2; ++g) {
      bf16x8 pa = *(const bf16x8*)&Ps[w][lr][g * 32 + 8 * lg];
#pragma unroll
      for (int dt = 0; dt < 4; ++dt) {
        bf16x8 bv = *(const bf16x8*)&Vs[dt * 16 + lr][g * 32 + 8 * lg];
        oacc[dt] = __builtin_amdgcn_mfma_f32_16x16x32_bf16(pa, bv, oacc[dt], 0, 0, 0);
      }
    }
  }
  const int b = bh / NH, h = bh % NH;
#pragma unroll
  for (int r = 0; r < 4; ++r) {
    float inv = 1.f / lsum[r];
    int row = q0 + w * 16 + lg * 4 + r;
    size_t obase = (size_t)(b * SEQ + row) * DIM + h * DH;
#pragma unroll
    for (int dt = 0; dt < 4; ++dt)
      Ob[obase + dt * 16 + lr] = f2bf(oacc[dt][r] * inv);
  }
}

extern "C" void kernel_launch(void* const* d_in, const int* in_sizes, int n_in,
                              void* d_out, int out_size, void* d_ws, size_t ws_size,
                              hipStream_t stream) {
  const float* x      = (const float*)d_in[0];
  const float* pos    = (const float*)d_in[1];
  const float* qkv_w  = (const float*)d_in[2];
  const float* proj_w = (const float*)d_in[3];
  const float* proj_b = (const float*)d_in[4];
  const float* qn_w   = (const float*)d_in[5];
  const float* kn_w   = (const float*)d_in[6];
  char* ws = (char*)d_ws;
  u16*   xb    = (u16*)(ws + 0);          // 4096*768*2  = 6291456
  u16*   wqkv  = (u16*)(ws + 6291456);    // 2304*768*2  = 3538944
  u16*   wproj = (u16*)(ws + 9830400);    // 768*768*2   = 1179648
  float* qkvf  = (float*)(ws + 11010048); // 4096*2304*4 = 37748736
  u16*   Qb    = (u16*)(ws + 48758784);   // 6291456
  u16*   Kb    = (u16*)(ws + 55050240);   // 6291456
  u16*   Vtb   = (u16*)(ws + 61341696);   // 6291456
  u16*   Ob    = (u16*)(ws + 67633152);   // 6291456 -> total 73924608
  float* out = (float*)d_out;

  conv_f2b<<<(TOK * DIM + 255) / 256, 256, 0, stream>>>(x, xb, TOK * DIM);
  conv_f2b<<<(QKVN * DIM + 255) / 256, 256, 0, stream>>>(qkv_w, wqkv, QKVN * DIM);
  conv_f2b<<<(DIM * DIM + 255) / 256, 256, 0, stream>>>(proj_w, wproj, DIM * DIM);

  dim3 g1(TOK / 64, QKVN / 64);
  gemm_bt<<<g1, 256, 0, stream>>>(xb, wqkv, qkvf, nullptr, TOK, QKVN, DIM);

  postproc<<<TOK, 256, 0, stream>>>(qkvf, pos, qn_w, kn_w, Qb, Kb, Vtb);

  dim3 g2(BATCH * NH, SEQ / 64);
  attn<<<g2, 256, 0, stream>>>(Qb, Kb, Vtb, Ob);

  dim3 g3(TOK / 64, DIM / 64);
  gemm_bt<<<g3, 256, 0, stream>>>(Ob, wproj, out, proj_b, TOK, DIM, DIM);
}

// Round 2
// 216.181 us; speedup vs baseline: 1.6613x; 1.6613x over previous
//
#include <hip/hip_runtime.h>
#include <hip/hip_bf16.h>
#include <math.h>

#define DIM 768
#define NH 12
#define DH 64
#define SEQ 2048
#define BATCH 2
#define TOK (BATCH*SEQ)   // 4096
#define QKVN (3*DIM)      // 2304

typedef __attribute__((ext_vector_type(8))) short bf16x8;
typedef __attribute__((ext_vector_type(4))) float f32x4;
typedef unsigned short u16;

__device__ inline u16 f2bf(float f) {
  union { float f; unsigned u; } v; v.f = f;
  unsigned u = v.u;
  u += 0x7fffu + ((u >> 16) & 1u);   // round-to-nearest-even
  return (u16)(u >> 16);
}

__global__ void conv_f2b(const float* __restrict__ in, u16* __restrict__ out, int n) {
  int i = (blockIdx.x * blockDim.x + threadIdx.x) * 4;
  if (i + 3 < n) {
    float4 v = *(const float4*)(in + i);
    ushort4 o;
    o.x = f2bf(v.x); o.y = f2bf(v.y); o.z = f2bf(v.z); o.w = f2bf(v.w);
    *(ushort4*)(out + i) = o;
  } else {
    for (; i < n; ++i) out[i] = f2bf(in[i]);
  }
}

#define GLL(g, s) __builtin_amdgcn_global_load_lds((const __attribute__((address_space(1))) void*)(g), (__attribute__((address_space(3))) void*)(s), 16, 0, 0)

// C[M][Nn] = A[M][K] * W[Nn][K]^T (+bias), bf16 in, fp32 out.
// m97 structure: 128x128 tile, BK=32, 4 waves (2x2), each wave 64x64 out,
// global_load_lds(16B) staging into linear LDS, 2 barriers / K-step.
__global__ __launch_bounds__(256) void gemm128(
    const u16* __restrict__ A, const u16* __restrict__ W,
    float* __restrict__ C, const float* __restrict__ bias,
    int M, int Nn, int K)
{
  __shared__ u16 As[128 * 32];
  __shared__ u16 Bs[128 * 32];
  const int t = threadIdx.x;
  const int w = t >> 6, l = t & 63;
  const int lr = l & 15, lg = l >> 4;
  const int wr = w >> 1, wc = w & 1;
  const int m0 = blockIdx.x * 128;
  const int n0 = blockIdx.y * 128;
  f32x4 acc[4][4] = {};
  // Staging: thread t covers tile bytes [t*16, t*16+16) of the 8KB half,
  // i.e. row t/4 (+64 for issue 1), cols (t%4)*8..+8. Linear LDS match.
  const int srow = t >> 2;
  const int scol = (t & 3) * 8;
  const u16* aSrc = A + (size_t)(m0 + srow) * K + scol;
  const u16* bSrc = W + (size_t)(n0 + srow) * K + scol;
  u16* aDst = As + w * 512;   // bytes: w*1024 + lane*16 (HW adds lane*16)
  u16* bDst = Bs + w * 512;
  const size_t rstep = (size_t)64 * K;

  for (int k0 = 0; k0 < K; k0 += 32) {
    __syncthreads();
    GLL(aSrc + k0,          aDst);
    GLL(aSrc + rstep + k0,  aDst + 2048);
    GLL(bSrc + k0,          bDst);
    GLL(bSrc + rstep + k0,  bDst + 2048);
    __syncthreads();
    bf16x8 af[4], bff[4];
#pragma unroll
    for (int mi = 0; mi < 4; ++mi)
      af[mi] = *(const bf16x8*)(As + (wr * 64 + mi * 16 + lr) * 32 + lg * 8);
#pragma unroll
    for (int ni = 0; ni < 4; ++ni)
      bff[ni] = *(const bf16x8*)(Bs + (wc * 64 + ni * 16 + lr) * 32 + lg * 8);
#pragma unroll
    for (int mi = 0; mi < 4; ++mi)
#pragma unroll
      for (int ni = 0; ni < 4; ++ni)
        acc[mi][ni] = __builtin_amdgcn_mfma_f32_16x16x32_bf16(af[mi], bff[ni], acc[mi][ni], 0, 0, 0);
  }

#pragma unroll
  for (int mi = 0; mi < 4; ++mi) {
#pragma unroll
    for (int ni = 0; ni < 4; ++ni) {
#pragma unroll
      for (int r = 0; r < 4; ++r) {
        int row = m0 + wr * 64 + mi * 16 + lg * 4 + r;
        int col = n0 + wc * 64 + ni * 16 + lr;
        float v = acc[mi][ni][r];
        if (bias) v += bias[col];
        C[(size_t)row * Nn + col] = v;
      }
    }
  }
}

// Per token: RMSNorm(q,k) per head + RoPE, emit Q,K as (B,H,N,DH) bf16 and V
// transposed as (B,H,DH,N) bf16. One wave handles one head (lane = d).
__global__ __launch_bounds__(256) void postproc(
    const float* __restrict__ qkv, const float* __restrict__ pos,
    const float* __restrict__ qn_w, const float* __restrict__ kn_w,
    u16* __restrict__ Qb, u16* __restrict__ Kb, u16* __restrict__ Vtb)
{
  const int t = blockIdx.x;            // token 0..4095
  const int w = threadIdx.x >> 6;      // wave 0..3
  const int d = threadIdx.x & 63;
  const int b = t >> 11, n = t & 2047;
  float cs = 1.f, sn = 0.f;
  if (d < 60) {
    const int p = d >> 1;
    const int axis = p / 10, fi = p % 10;
    float freq = exp2f(-(float)fi * 1.3287712379549449f); // log2(10000)/10
    float ang = pos[t * 3 + axis] * freq;
    cs = cosf(ang); sn = sinf(ang);
  }
  const float qw = qn_w[d], kw = kn_w[d];
  for (int hh = 0; hh < 3; ++hh) {
    const int h = w + hh * 4;
    const float* base = qkv + (size_t)t * QKVN + h * DH + d;
    float q = base[0], k = base[DIM], v = base[2 * DIM];
    float sq = q * q, sk = k * k;
#pragma unroll
    for (int off = 32; off >= 1; off >>= 1) {
      sq += __shfl_xor(sq, off, 64);
      sk += __shfl_xor(sk, off, 64);
    }
    float qn = q * rsqrtf(sq * (1.f / 64.f) + 1e-6f) * qw;
    float kn = k * rsqrtf(sk * (1.f / 64.f) + 1e-6f) * kw;
    float qo = __shfl_xor(qn, 1, 64);
    float ko = __shfl_xor(kn, 1, 64);
    float qr = qn, kr = kn;
    if (d < 60) {
      if (d & 1) { qr = qo * sn + qn * cs; kr = ko * sn + kn * cs; }
      else       { qr = qn * cs - qo * sn; kr = kn * cs - ko * sn; }
    }
    const size_t bh = (size_t)(b * NH + h);
    Qb[(bh * SEQ + n) * DH + d] = f2bf(qr);
    Kb[(bh * SEQ + n) * DH + d] = f2bf(kr);
    Vtb[(bh * DH + d) * SEQ + n] = f2bf(v);
  }
}

// Flash attention. Grid (B*H, N/64). 4 waves, each owns 16 Q rows.
#define NPAD 72
__global__ __launch_bounds__(256) void attn(
    const u16* __restrict__ Qb, const u16* __restrict__ Kb,
    const u16* __restrict__ Vtb, u16* __restrict__ Ob)
{
  __shared__ u16 Ks[64][NPAD];
  __shared__ u16 Vs[64][NPAD];   // Vs[d][kk]
  __shared__ u16 Ps[4][16][NPAD];
  const int w = threadIdx.x >> 6, l = threadIdx.x & 63;
  const int lr = l & 15, lg = l >> 4;
  const int bh = blockIdx.x;
  const int q0 = blockIdx.y * 64;
  const u16* Qp = Qb + (size_t)bh * SEQ * DH;
  const u16* Kp = Kb + (size_t)bh * SEQ * DH;
  const u16* Vp = Vtb + (size_t)bh * DH * SEQ;
  const int qr = q0 + w * 16 + lr;
  const bf16x8 aq0 = *(const bf16x8*)(Qp + qr * DH + 8 * lg);
  const bf16x8 aq1 = *(const bf16x8*)(Qp + qr * DH + 32 + 8 * lg);
  float mrow[4], lsum[4];
  f32x4 oacc[4] = {};
#pragma unroll
  for (int r = 0; r < 4; ++r) { mrow[r] = -1e30f; lsum[r] = 0.f; }
  const int srow = threadIdx.x >> 2;          // 0..63
  const int scol = (threadIdx.x & 3) * 16;    // 0,16,32,48
  for (int kt = 0; kt < 32; ++kt) {
    const int kk0 = kt * 64;
    __syncthreads();
    *(bf16x8*)&Ks[srow][scol]     = *(const bf16x8*)(Kp + (size_t)(kk0 + srow) * DH + scol);
    *(bf16x8*)&Ks[srow][scol + 8] = *(const bf16x8*)(Kp + (size_t)(kk0 + srow) * DH + scol + 8);
    *(bf16x8*)&Vs[srow][scol]     = *(const bf16x8*)(Vp + (size_t)srow * SEQ + kk0 + scol);
    *(bf16x8*)&Vs[srow][scol + 8] = *(const bf16x8*)(Vp + (size_t)srow * SEQ + kk0 + scol + 8);
    __syncthreads();
    f32x4 s[4] = {};
#pragma unroll
    for (int c = 0; c < 4; ++c) {
      bf16x8 bk0 = *(const bf16x8*)&Ks[c * 16 + lr][8 * lg];
      bf16x8 bk1 = *(const bf16x8*)&Ks[c * 16 + lr][32 + 8 * lg];
      s[c] = __builtin_amdgcn_mfma_f32_16x16x32_bf16(aq0, bk0, s[c], 0, 0, 0);
      s[c] = __builtin_amdgcn_mfma_f32_16x16x32_bf16(aq1, bk1, s[c], 0, 0, 0);
    }
#pragma unroll
    for (int r = 0; r < 4; ++r) {
      float s0 = s[0][r] * 0.125f, s1 = s[1][r] * 0.125f;
      float s2 = s[2][r] * 0.125f, s3 = s[3][r] * 0.125f;
      float mx = fmaxf(fmaxf(s0, s1), fmaxf(s2, s3));
      mx = fmaxf(mx, __shfl_xor(mx, 1, 64));
      mx = fmaxf(mx, __shfl_xor(mx, 2, 64));
      mx = fmaxf(mx, __shfl_xor(mx, 4, 64));
      mx = fmaxf(mx, __shfl_xor(mx, 8, 64));
      float mnew = fmaxf(mrow[r], mx);
      float fsc = expf(mrow[r] - mnew);
      mrow[r] = mnew;
      float p0 = expf(s0 - mnew), p1 = expf(s1 - mnew);
      float p2 = expf(s2 - mnew), p3 = expf(s3 - mnew);
      const int prow = lg * 4 + r;
      Ps[w][prow][0 + lr]  = f2bf(p0);
      Ps[w][prow][16 + lr] = f2bf(p1);
      Ps[w][prow][32 + lr] = f2bf(p2);
      Ps[w][prow][48 + lr] = f2bf(p3);
      float psum = p0 + p1 + p2 + p3;
      psum += __shfl_xor(psum, 1, 64);
      psum += __shfl_xor(psum, 2, 64);
      psum += __shfl_xor(psum, 4, 64);
      psum += __shfl_xor(psum, 8, 64);
      lsum[r] = lsum[r] * fsc + psum;
#pragma unroll
      for (int dt = 0; dt < 4; ++dt) oacc[dt][r] *= fsc;
    }
    __syncthreads();   // make Ps visible (cross-lane via LDS)
#pragma unroll
    for (int g = 0; g < 2; ++g) {
      bf16x8 pa = *(const bf16x8*)&Ps[w][lr][g * 32 + 8 * lg];
#pragma unroll
      for (int dt = 0; dt < 4; ++dt) {
        bf16x8 bv = *(const bf16x8*)&Vs[dt * 16 + lr][g * 32 + 8 * lg];
        oacc[dt] = __builtin_amdgcn_mfma_f32_16x16x32_bf16(pa, bv, oacc[dt], 0, 0, 0);
      }
    }
  }
  const int b = bh / NH, h = bh % NH;
#pragma unroll
  for (int r = 0; r < 4; ++r) {
    float inv = 1.f / lsum[r];
    int row = q0 + w * 16 + lg * 4 + r;
    size_t obase = (size_t)(b * SEQ + row) * DIM + h * DH;
#pragma unroll
    for (int dt = 0; dt < 4; ++dt)
      Ob[obase + dt * 16 + lr] = f2bf(oacc[dt][r] * inv);
  }
}

extern "C" void kernel_launch(void* const* d_in, const int* in_sizes, int n_in,
                              void* d_out, int out_size, void* d_ws, size_t ws_size,
                              hipStream_t stream) {
  const float* x      = (const float*)d_in[0];
  const float* pos    = (const float*)d_in[1];
  const float* qkv_w  = (const float*)d_in[2];
  const float* proj_w = (const float*)d_in[3];
  const float* proj_b = (const float*)d_in[4];
  const float* qn_w   = (const float*)d_in[5];
  const float* kn_w   = (const float*)d_in[6];
  char* ws = (char*)d_ws;
  u16*   xb    = (u16*)(ws + 0);          // 4096*768*2  = 6291456
  u16*   wqkv  = (u16*)(ws + 6291456);    // 2304*768*2  = 3538944
  u16*   wproj = (u16*)(ws + 9830400);    // 768*768*2   = 1179648
  float* qkvf  = (float*)(ws + 11010048); // 4096*2304*4 = 37748736
  u16*   Qb    = (u16*)(ws + 48758784);   // 6291456
  u16*   Kb    = (u16*)(ws + 55050240);   // 6291456
  u16*   Vtb   = (u16*)(ws + 61341696);   // 6291456
  u16*   Ob    = (u16*)(ws + 67633152);   // 6291456 -> total 73924608
  float* out = (float*)d_out;

  conv_f2b<<<(TOK * DIM / 4 + 255) / 256, 256, 0, stream>>>(x, xb, TOK * DIM);
  conv_f2b<<<(QKVN * DIM / 4 + 255) / 256, 256, 0, stream>>>(qkv_w, wqkv, QKVN * DIM);
  conv_f2b<<<(DIM * DIM / 4 + 255) / 256, 256, 0, stream>>>(proj_w, wproj, DIM * DIM);

  dim3 g1(TOK / 128, QKVN / 128);
  gemm128<<<g1, 256, 0, stream>>>(xb, wqkv, qkvf, nullptr, TOK, QKVN, DIM);

  postproc<<<TOK, 256, 0, stream>>>(qkvf, pos, qn_w, kn_w, Qb, Kb, Vtb);

  dim3 g2(BATCH * NH, SEQ / 64);
  attn<<<g2, 256, 0, stream>>>(Qb, Kb, Vtb, Ob);

  dim3 g3(TOK / 128, DIM / 128);
  gemm128<<<g3, 256, 0, stream>>>(Ob, wproj, out, proj_b, TOK, DIM, DIM);
}

// Round 3
// 147.880 us; speedup vs baseline: 2.4286x; 1.4619x over previous
//
#include <hip/hip_runtime.h>
#include <hip/hip_bf16.h>
#include <math.h>

#define DIM 768
#define NH 12
#define DH 64
#define SEQ 2048
#define BATCH 2
#define TOK (BATCH*SEQ)   // 4096
#define QKVN (3*DIM)      // 2304

typedef __attribute__((ext_vector_type(8))) short bf16x8;
typedef __attribute__((ext_vector_type(4))) float f32x4;
typedef unsigned short u16;

__device__ inline u16 f2bf(float f) {
  union { float f; unsigned u; } v; v.f = f;
  unsigned u = v.u;
  u += 0x7fffu + ((u >> 16) & 1u);   // round-to-nearest-even
  return (u16)(u >> 16);
}

__device__ inline int pkbf(float a, float b) {   // packed bf16 pair (RNE)
  __hip_bfloat162 h = __float22bfloat162_rn(make_float2(a, b));
  int r; __builtin_memcpy(&r, &h, 4); return r;
}

__global__ void conv_f2b(const float* __restrict__ in, u16* __restrict__ out, int n) {
  int i = (blockIdx.x * blockDim.x + threadIdx.x) * 4;
  if (i + 3 < n) {
    float4 v = *(const float4*)(in + i);
    ushort4 o;
    o.x = f2bf(v.x); o.y = f2bf(v.y); o.z = f2bf(v.z); o.w = f2bf(v.w);
    *(ushort4*)(out + i) = o;
  } else {
    for (; i < n; ++i) out[i] = f2bf(in[i]);
  }
}

#define GLL(g, s) __builtin_amdgcn_global_load_lds((const __attribute__((address_space(1))) void*)(g), (__attribute__((address_space(3))) void*)(s), 16, 0, 0)

// C[M][Nn] = A[M][K] * W[Nn][K]^T (+bias), bf16 in, fp32 out. m97 structure.
__global__ __launch_bounds__(256) void gemm128(
    const u16* __restrict__ A, const u16* __restrict__ W,
    float* __restrict__ C, const float* __restrict__ bias,
    int M, int Nn, int K)
{
  __shared__ u16 As[128 * 32];
  __shared__ u16 Bs[128 * 32];
  const int t = threadIdx.x;
  const int w = t >> 6, l = t & 63;
  const int lr = l & 15, lg = l >> 4;
  const int wr = w >> 1, wc = w & 1;
  const int m0 = blockIdx.x * 128;
  const int n0 = blockIdx.y * 128;
  f32x4 acc[4][4] = {};
  const int srow = t >> 2;
  const int scol = (t & 3) * 8;
  const u16* aSrc = A + (size_t)(m0 + srow) * K + scol;
  const u16* bSrc = W + (size_t)(n0 + srow) * K + scol;
  u16* aDst = As + w * 512;
  u16* bDst = Bs + w * 512;
  const size_t rstep = (size_t)64 * K;

  for (int k0 = 0; k0 < K; k0 += 32) {
    __syncthreads();
    GLL(aSrc + k0,          aDst);
    GLL(aSrc + rstep + k0,  aDst + 2048);
    GLL(bSrc + k0,          bDst);
    GLL(bSrc + rstep + k0,  bDst + 2048);
    __syncthreads();
    bf16x8 af[4], bff[4];
#pragma unroll
    for (int mi = 0; mi < 4; ++mi)
      af[mi] = *(const bf16x8*)(As + (wr * 64 + mi * 16 + lr) * 32 + lg * 8);
#pragma unroll
    for (int ni = 0; ni < 4; ++ni)
      bff[ni] = *(const bf16x8*)(Bs + (wc * 64 + ni * 16 + lr) * 32 + lg * 8);
#pragma unroll
    for (int mi = 0; mi < 4; ++mi)
#pragma unroll
      for (int ni = 0; ni < 4; ++ni)
        acc[mi][ni] = __builtin_amdgcn_mfma_f32_16x16x32_bf16(af[mi], bff[ni], acc[mi][ni], 0, 0, 0);
  }

#pragma unroll
  for (int mi = 0; mi < 4; ++mi) {
#pragma unroll
    for (int ni = 0; ni < 4; ++ni) {
#pragma unroll
      for (int r = 0; r < 4; ++r) {
        int row = m0 + wr * 64 + mi * 16 + lg * 4 + r;
        int col = n0 + wc * 64 + ni * 16 + lr;
        float v = acc[mi][ni][r];
        if (bias) v += bias[col];
        C[(size_t)row * Nn + col] = v;
      }
    }
  }
}

// RMSNorm(q,k) + RoPE. Q gets the attention scale folded in:
// SCALE = 0.125 * log2(e), so S' = Q'.K is directly in exp2 domain.
__global__ __launch_bounds__(256) void postproc(
    const float* __restrict__ qkv, const float* __restrict__ pos,
    const float* __restrict__ qn_w, const float* __restrict__ kn_w,
    u16* __restrict__ Qb, u16* __restrict__ Kb, u16* __restrict__ Vtb)
{
  const int t = blockIdx.x;
  const int w = threadIdx.x >> 6;
  const int d = threadIdx.x & 63;
  const int b = t >> 11, n = t & 2047;
  const float QSCALE = 0.125f * 1.4426950408889634f;
  float cs = 1.f, sn = 0.f;
  if (d < 60) {
    const int p = d >> 1;
    const int axis = p / 10, fi = p % 10;
    float freq = exp2f(-(float)fi * 1.3287712379549449f); // log2(10000)/10
    float ang = pos[t * 3 + axis] * freq;
    cs = cosf(ang); sn = sinf(ang);
  }
  const float qw = qn_w[d], kw = kn_w[d];
  for (int hh = 0; hh < 3; ++hh) {
    const int h = w + hh * 4;
    const float* base = qkv + (size_t)t * QKVN + h * DH + d;
    float q = base[0], k = base[DIM], v = base[2 * DIM];
    float sq = q * q, sk = k * k;
#pragma unroll
    for (int off = 32; off >= 1; off >>= 1) {
      sq += __shfl_xor(sq, off, 64);
      sk += __shfl_xor(sk, off, 64);
    }
    float qn = q * rsqrtf(sq * (1.f / 64.f) + 1e-6f) * qw;
    float kn = k * rsqrtf(sk * (1.f / 64.f) + 1e-6f) * kw;
    float qo = __shfl_xor(qn, 1, 64);
    float ko = __shfl_xor(kn, 1, 64);
    float qr = qn, kr = kn;
    if (d < 60) {
      if (d & 1) { qr = qo * sn + qn * cs; kr = ko * sn + kn * cs; }
      else       { qr = qn * cs - qo * sn; kr = kn * cs - ko * sn; }
    }
    qr *= QSCALE;
    const size_t bh = (size_t)(b * NH + h);
    Qb[(bh * SEQ + n) * DH + d] = f2bf(qr);
    Kb[(bh * SEQ + n) * DH + d] = f2bf(kr);
    Vtb[(bh * DH + d) * SEQ + n] = f2bf(v);
  }
}

// Flash attention, swapped-operand form. Grid (SEQ/64, B*H), 4 waves x 16 q-rows.
// S^T = mfma(K,Q) with K-rows bit2<->3 permuted so the PV B-frag (P^T) is
// buildable from in-lane values + one lane^32 exchange. Softmax uses a static
// max shift (||q||=||k||=8 with w=1 => |S|<=8 => exp2 arg in [-24,0)), which
// is mathematically exact for softmax (constant shift cancels). No P LDS
// bounce, no max reduction, no rescale. K/V staged via global_load_lds with
// XOR-swizzled source (linear dest), reads XOR back => 2-way banks only.
__global__ __launch_bounds__(256) void attn(
    const u16* __restrict__ Qb, const u16* __restrict__ Kb,
    const u16* __restrict__ Vtb, u16* __restrict__ Ob)
{
  __shared__ u16 Ks[64 * 64];
  __shared__ u16 Vs[64 * 64];
  const int tid = threadIdx.x;
  const int w = tid >> 6, l = tid & 63;
  const int lr = l & 15, lg = l >> 4;
  const int bh = blockIdx.y;
  const int q0 = blockIdx.x * 64;
  const u16* Qp = Qb + (size_t)bh * SEQ * DH;
  const u16* Kp = Kb + (size_t)bh * SEQ * DH;
  const u16* Vp = Vtb + (size_t)bh * DH * SEQ;

  // Q B-frag: col = q = lr, k(d) = 8*lg+j. Loaded once.
  const int qrow = q0 + w * 16 + lr;
  const bf16x8 bq0 = *(const bf16x8*)(Qp + (size_t)qrow * DH + 8 * lg);
  const bf16x8 bq1 = *(const bf16x8*)(Qp + (size_t)qrow * DH + 32 + 8 * lg);

  // staging source (pre-swizzled): thread t -> LDS chunk t (row t/8, col16 t%8)
  const int srow = tid >> 3;
  const int sc16 = (tid & 7) ^ (srow & 7);
  const u16* kSrc = Kp + (size_t)srow * DH + sc16 * 8;             // + kt*4096
  const u16* vSrc = Vp + (size_t)srow * SEQ + sc16 * 8;            // + kt*64
  u16* kDst = Ks + w * 512;
  u16* vDst = Vs + w * 512;

  // K A-frag read constants: row = 16c + frow (bit2<->3 swap of lr)
  const int frow = (lr & 3) | ((lr & 4) << 1) | ((lr & 8) >> 1);
  const int ksw = frow & 7;
  const int vsw = lr & 7;

  f32x4 oacc[4] = {};
  float lsum = 0.f;

  for (int kt = 0; kt < 32; ++kt) {
    __syncthreads();
    GLL(kSrc + kt * 4096,         kDst);
    GLL(kSrc + kt * 4096 + 2048,  kDst + 2048);
    GLL(vSrc + kt * 64,           vDst);
    GLL(vSrc + kt * 64 + 65536,   vDst + 2048);
    __syncthreads();

    // S^T tiles: pacc[c] cols=q(lr), rows=kk(4lg+r) -> physical k=16c+f(4lg+r)
    f32x4 pacc[4] = {};
#pragma unroll
    for (int c = 0; c < 4; ++c) {
      const int rbase = (16 * c + frow) * 64;
      bf16x8 ka = *(const bf16x8*)(Ks + rbase + ((lg ^ ksw) * 8));
      bf16x8 kb = *(const bf16x8*)(Ks + rbase + (((4 + lg) ^ ksw) * 8));
      pacc[c] = __builtin_amdgcn_mfma_f32_16x16x32_bf16(ka, bq0, pacc[c], 0, 0, 0);
      pacc[c] = __builtin_amdgcn_mfma_f32_16x16x32_bf16(kb, bq1, pacc[c], 0, 0, 0);
    }
    // p = 2^(s' - 12), exact softmax shift
    float p[4][4];
#pragma unroll
    for (int c = 0; c < 4; ++c)
#pragma unroll
      for (int r = 0; r < 4; ++r) {
        float pv = __builtin_amdgcn_exp2f(pacc[c][r] - 12.f);
        p[c][r] = pv;
        lsum += pv;
      }
    // Build P^T B-frags (g=0: k0..31 from c=0,1; g=1: k32..63 from c=2,3)
#pragma unroll
    for (int g = 0; g < 2; ++g) {
      const int clo = 2 * g, chi = 2 * g + 1;
      int x01 = pkbf(p[clo][0], p[clo][1]);
      int x23 = pkbf(p[clo][2], p[clo][3]);
      int y01 = pkbf(p[chi][0], p[chi][1]);
      int y23 = pkbf(p[chi][2], p[chi][3]);
      int xp01 = __shfl_xor(x01, 32, 64);
      int xp23 = __shfl_xor(x23, 32, 64);
      int yp01 = __shfl_xor(y01, 32, 64);
      int yp23 = __shfl_xor(y23, 32, 64);
      const bool lo = (l < 32);
      union { int d[4]; bf16x8 v; } pu;
      pu.d[0] = lo ? x01 : yp01;
      pu.d[1] = lo ? x23 : yp23;
      pu.d[2] = lo ? xp01 : y01;
      pu.d[3] = lo ? xp23 : y23;
      // O^T += mfma(Vt rows d, P^T): A row = d = 16dt+lr, k = 32g+8lg+j
#pragma unroll
      for (int dt = 0; dt < 4; ++dt) {
        bf16x8 va = *(const bf16x8*)(Vs + (16 * dt + lr) * 64 + (((4 * g + lg) ^ vsw) * 8));
        oacc[dt] = __builtin_amdgcn_mfma_f32_16x16x32_bf16(va, pu.v, oacc[dt], 0, 0, 0);
      }
    }
  }

  // row sum: lanes l, l^16, l^32, l^48 share q-row lr
  lsum += __shfl_xor(lsum, 16, 64);
  lsum += __shfl_xor(lsum, 32, 64);
  const float inv = 1.f / lsum;
  const int b = bh / NH, h = bh % NH;
  const int q = q0 + w * 16 + lr;
  size_t obase = (size_t)(b * SEQ + q) * DIM + h * DH + 4 * lg;
#pragma unroll
  for (int dt = 0; dt < 4; ++dt) {
    ushort4 o;
    o.x = f2bf(oacc[dt][0] * inv);
    o.y = f2bf(oacc[dt][1] * inv);
    o.z = f2bf(oacc[dt][2] * inv);
    o.w = f2bf(oacc[dt][3] * inv);
    *(ushort4*)(Ob + obase + 16 * dt) = o;
  }
}

extern "C" void kernel_launch(void* const* d_in, const int* in_sizes, int n_in,
                              void* d_out, int out_size, void* d_ws, size_t ws_size,
                              hipStream_t stream) {
  const float* x      = (const float*)d_in[0];
  const float* pos    = (const float*)d_in[1];
  const float* qkv_w  = (const float*)d_in[2];
  const float* proj_w = (const float*)d_in[3];
  const float* proj_b = (const float*)d_in[4];
  const float* qn_w   = (const float*)d_in[5];
  const float* kn_w   = (const float*)d_in[6];
  char* ws = (char*)d_ws;
  u16*   xb    = (u16*)(ws + 0);
  u16*   wqkv  = (u16*)(ws + 6291456);
  u16*   wproj = (u16*)(ws + 9830400);
  float* qkvf  = (float*)(ws + 11010048);
  u16*   Qb    = (u16*)(ws + 48758784);
  u16*   Kb    = (u16*)(ws + 55050240);
  u16*   Vtb   = (u16*)(ws + 61341696);
  u16*   Ob    = (u16*)(ws + 67633152);
  float* out = (float*)d_out;

  conv_f2b<<<(TOK * DIM / 4 + 255) / 256, 256, 0, stream>>>(x, xb, TOK * DIM);
  conv_f2b<<<(QKVN * DIM / 4 + 255) / 256, 256, 0, stream>>>(qkv_w, wqkv, QKVN * DIM);
  conv_f2b<<<(DIM * DIM / 4 + 255) / 256, 256, 0, stream>>>(proj_w, wproj, DIM * DIM);

  dim3 g1(TOK / 128, QKVN / 128);
  gemm128<<<g1, 256, 0, stream>>>(xb, wqkv, qkvf, nullptr, TOK, QKVN, DIM);

  postproc<<<TOK, 256, 0, stream>>>(qkvf, pos, qn_w, kn_w, Qb, Kb, Vtb);

  dim3 g2(SEQ / 64, BATCH * NH);
  attn<<<g2, 256, 0, stream>>>(Qb, Kb, Vtb, Ob);

  dim3 g3(TOK / 128, DIM / 128);
  gemm128<<<g3, 256, 0, stream>>>(Ob, wproj, out, proj_b, TOK, DIM, DIM);
}

// Round 4
// 139.504 us; speedup vs baseline: 2.5744x; 1.0600x over previous
//
#include <hip/hip_runtime.h>
#include <hip/hip_bf16.h>
#include <math.h>

#define DIM 768
#define NH 12
#define DH 64
#define SEQ 2048
#define BATCH 2
#define TOK (BATCH*SEQ)   // 4096
#define QKVN (3*DIM)      // 2304

typedef __attribute__((ext_vector_type(8))) short bf16x8;
typedef __attribute__((ext_vector_type(4))) float f32x4;
typedef unsigned short u16;

__device__ inline u16 f2bf(float f) {
  union { float f; unsigned u; } v; v.f = f;
  unsigned u = v.u;
  u += 0x7fffu + ((u >> 16) & 1u);   // round-to-nearest-even
  return (u16)(u >> 16);
}

__device__ inline float bf2f(u16 h) {
  union { unsigned u; float f; } v; v.u = ((unsigned)h) << 16; return v.f;
}

__device__ inline int pkbf(float a, float b) {   // packed bf16 pair (RNE)
  __hip_bfloat162 h = __float22bfloat162_rn(make_float2(a, b));
  int r; __builtin_memcpy(&r, &h, 4); return r;
}

// One launch converts x, qkv_w, proj_w.
__global__ void conv_all(const float* __restrict__ a, u16* __restrict__ ao, int na4,
                         const float* __restrict__ b, u16* __restrict__ bo, int nb4,
                         const float* __restrict__ c, u16* __restrict__ co, int nc4) {
  int i4 = blockIdx.x * blockDim.x + threadIdx.x;
  const float* src; u16* dst; int off;
  if (i4 < na4)            { src = a; dst = ao; off = i4; }
  else if (i4 < na4 + nb4) { src = b; dst = bo; off = i4 - na4; }
  else if (i4 < na4 + nb4 + nc4) { src = c; dst = co; off = i4 - na4 - nb4; }
  else return;
  float4 v = ((const float4*)src)[off];
  ushort4 o;
  o.x = f2bf(v.x); o.y = f2bf(v.y); o.z = f2bf(v.z); o.w = f2bf(v.w);
  ((ushort4*)dst)[off] = o;
}

#define GLL(g, s) __builtin_amdgcn_global_load_lds((const __attribute__((address_space(1))) void*)(g), (__attribute__((address_space(3))) void*)(s), 16, 0, 0)

// C[M][Nn] = A[M][K] * W[Nn][K]^T (+bias), bf16 in, fp32 or bf16 out.
template<bool BF16OUT>
__global__ __launch_bounds__(256) void gemm128(
    const u16* __restrict__ A, const u16* __restrict__ W,
    void* __restrict__ Cv, const float* __restrict__ bias,
    int M, int Nn, int K)
{
  __shared__ u16 As[128 * 32];
  __shared__ u16 Bs[128 * 32];
  const int t = threadIdx.x;
  const int w = t >> 6, l = t & 63;
  const int lr = l & 15, lg = l >> 4;
  const int wr = w >> 1, wc = w & 1;
  const int m0 = blockIdx.x * 128;
  const int n0 = blockIdx.y * 128;
  f32x4 acc[4][4] = {};
  const int srow = t >> 2;
  const int scol = (t & 3) * 8;
  const u16* aSrc = A + (size_t)(m0 + srow) * K + scol;
  const u16* bSrc = W + (size_t)(n0 + srow) * K + scol;
  u16* aDst = As + w * 512;
  u16* bDst = Bs + w * 512;
  const size_t rstep = (size_t)64 * K;

  for (int k0 = 0; k0 < K; k0 += 32) {
    __syncthreads();
    GLL(aSrc + k0,          aDst);
    GLL(aSrc + rstep + k0,  aDst + 2048);
    GLL(bSrc + k0,          bDst);
    GLL(bSrc + rstep + k0,  bDst + 2048);
    __syncthreads();
    bf16x8 af[4], bff[4];
#pragma unroll
    for (int mi = 0; mi < 4; ++mi)
      af[mi] = *(const bf16x8*)(As + (wr * 64 + mi * 16 + lr) * 32 + lg * 8);
#pragma unroll
    for (int ni = 0; ni < 4; ++ni)
      bff[ni] = *(const bf16x8*)(Bs + (wc * 64 + ni * 16 + lr) * 32 + lg * 8);
#pragma unroll
    for (int mi = 0; mi < 4; ++mi)
#pragma unroll
      for (int ni = 0; ni < 4; ++ni)
        acc[mi][ni] = __builtin_amdgcn_mfma_f32_16x16x32_bf16(af[mi], bff[ni], acc[mi][ni], 0, 0, 0);
  }

#pragma unroll
  for (int mi = 0; mi < 4; ++mi) {
#pragma unroll
    for (int ni = 0; ni < 4; ++ni) {
#pragma unroll
      for (int r = 0; r < 4; ++r) {
        int row = m0 + wr * 64 + mi * 16 + lg * 4 + r;
        int col = n0 + wc * 64 + ni * 16 + lr;
        float v = acc[mi][ni][r];
        if constexpr (BF16OUT) {
          ((u16*)Cv)[(size_t)row * Nn + col] = f2bf(v);
        } else {
          if (bias) v += bias[col];
          ((float*)Cv)[(size_t)row * Nn + col] = v;
        }
      }
    }
  }
}

// RMSNorm(q,k) + RoPE from bf16 qkv. Q gets 0.125*log2(e) folded in.
__global__ __launch_bounds__(256) void postproc(
    const u16* __restrict__ qkv, const float* __restrict__ pos,
    const float* __restrict__ qn_w, const float* __restrict__ kn_w,
    u16* __restrict__ Qb, u16* __restrict__ Kb, u16* __restrict__ Vtb)
{
  const int t = blockIdx.x;
  const int w = threadIdx.x >> 6;
  const int d = threadIdx.x & 63;
  const int b = t >> 11, n = t & 2047;
  const float QSCALE = 0.125f * 1.4426950408889634f;
  float cs = 1.f, sn = 0.f;
  if (d < 60) {
    const int p = d >> 1;
    const int axis = p / 10, fi = p % 10;
    float freq = exp2f(-(float)fi * 1.3287712379549449f); // log2(10000)/10
    float ang = pos[t * 3 + axis] * freq;
    cs = cosf(ang); sn = sinf(ang);
  }
  const float qw = qn_w[d], kw = kn_w[d];
  for (int hh = 0; hh < 3; ++hh) {
    const int h = w + hh * 4;
    const u16* base = qkv + (size_t)t * QKVN + h * DH + d;
    float q = bf2f(base[0]), k = bf2f(base[DIM]), v = bf2f(base[2 * DIM]);
    float sq = q * q, sk = k * k;
#pragma unroll
    for (int off = 32; off >= 1; off >>= 1) {
      sq += __shfl_xor(sq, off, 64);
      sk += __shfl_xor(sk, off, 64);
    }
    float qn = q * rsqrtf(sq * (1.f / 64.f) + 1e-6f) * qw;
    float kn = k * rsqrtf(sk * (1.f / 64.f) + 1e-6f) * kw;
    float qo = __shfl_xor(qn, 1, 64);
    float ko = __shfl_xor(kn, 1, 64);
    float qr = qn, kr = kn;
    if (d < 60) {
      if (d & 1) { qr = qo * sn + qn * cs; kr = ko * sn + kn * cs; }
      else       { qr = qn * cs - qo * sn; kr = kn * cs - ko * sn; }
    }
    qr *= QSCALE;
    const size_t bh = (size_t)(b * NH + h);
    Qb[(bh * SEQ + n) * DH + d] = f2bf(qr);
    Kb[(bh * SEQ + n) * DH + d] = f2bf(kr);
    Vtb[(bh * DH + d) * SEQ + n] = f2bf(v);
  }
}

// Flash attention, swapped-operand, static-shift softmax (exact).
// 1-D grid 768 with XCD swizzle: each XCD owns 96 consecutive blocks = 3 heads
// -> K/V L2-resident per XCD. 2-phase LDS double-buffer: stage(t+1) issued
// before compute(t), single barrier per tile (vmcnt drain hides under compute).
__global__ __launch_bounds__(256) void attn(
    const u16* __restrict__ Qb, const u16* __restrict__ Kb,
    const u16* __restrict__ Vtb, u16* __restrict__ Ob)
{
  __shared__ u16 Ks[2][64 * 64];
  __shared__ u16 Vs[2][64 * 64];
  const int tid = threadIdx.x;
  const int w = tid >> 6, l = tid & 63;
  const int lr = l & 15, lg = l >> 4;
  const int wg = blockIdx.x;
  const int swz = (wg & 7) * 96 + (wg >> 3);   // bijective, 768 % 8 == 0
  const int bh = swz >> 5;                      // /32
  const int q0 = (swz & 31) * 64;
  const u16* Qp = Qb + (size_t)bh * SEQ * DH;
  const u16* Kp = Kb + (size_t)bh * SEQ * DH;
  const u16* Vp = Vtb + (size_t)bh * DH * SEQ;

  // Q B-frag: col = q = lr, k(d) = 8*lg+j. Loaded once.
  const int qrow = q0 + w * 16 + lr;
  const bf16x8 bq0 = *(const bf16x8*)(Qp + (size_t)qrow * DH + 8 * lg);
  const bf16x8 bq1 = *(const bf16x8*)(Qp + (size_t)qrow * DH + 32 + 8 * lg);

  // staging source (pre-swizzled): thread t -> LDS chunk t (row t/8, col16 t%8)
  const int srow = tid >> 3;
  const int sc16 = (tid & 7) ^ (srow & 7);
  const u16* kSrc = Kp + (size_t)srow * DH + sc16 * 8;    // + kt*4096
  const u16* vSrc = Vp + (size_t)srow * SEQ + sc16 * 8;   // + kt*64

  // K A-frag read constants: row = 16c + frow (bit2<->3 swap of lr)
  const int frow = (lr & 3) | ((lr & 4) << 1) | ((lr & 8) >> 1);
  const int ksw = frow & 7;
  const int vsw = lr & 7;

  f32x4 oacc[4] = {};
  float lsum = 0.f;

  // prologue: stage tile 0 into buf 0
  {
    u16* kD = &Ks[0][w * 512];
    u16* vD = &Vs[0][w * 512];
    GLL(kSrc,         kD);
    GLL(kSrc + 2048,  kD + 2048);
    GLL(vSrc,         vD);
    GLL(vSrc + 65536, vD + 2048);
  }
  __syncthreads();

  for (int kt = 0; kt < 32; ++kt) {
    const int cur = kt & 1;
    if (kt + 1 < 32) {
      u16* kD = &Ks[cur ^ 1][w * 512];
      u16* vD = &Vs[cur ^ 1][w * 512];
      GLL(kSrc + (kt + 1) * 4096,         kD);
      GLL(kSrc + (kt + 1) * 4096 + 2048,  kD + 2048);
      GLL(vSrc + (kt + 1) * 64,           vD);
      GLL(vSrc + (kt + 1) * 64 + 65536,   vD + 2048);
    }
    const u16* Kt = &Ks[cur][0];
    const u16* Vt = &Vs[cur][0];

    // S^T tiles: pacc[c] cols=q(lr), rows=kk(4lg+r) -> physical k=16c+f(4lg+r)
    f32x4 pacc[4] = {};
#pragma unroll
    for (int c = 0; c < 4; ++c) {
      const int rbase = (16 * c + frow) * 64;
      bf16x8 ka = *(const bf16x8*)(Kt + rbase + ((lg ^ ksw) * 8));
      bf16x8 kb = *(const bf16x8*)(Kt + rbase + (((4 + lg) ^ ksw) * 8));
      pacc[c] = __builtin_amdgcn_mfma_f32_16x16x32_bf16(ka, bq0, pacc[c], 0, 0, 0);
      pacc[c] = __builtin_amdgcn_mfma_f32_16x16x32_bf16(kb, bq1, pacc[c], 0, 0, 0);
    }
    // p = 2^(s' - 12), exact softmax shift (|S'| <= 11.54)
    float p[4][4];
#pragma unroll
    for (int c = 0; c < 4; ++c)
#pragma unroll
      for (int r = 0; r < 4; ++r) {
        float pv = __builtin_amdgcn_exp2f(pacc[c][r] - 12.f);
        p[c][r] = pv;
        lsum += pv;
      }
    // Build P^T B-frags and accumulate O^T = mfma(Vt, P^T)
#pragma unroll
    for (int g = 0; g < 2; ++g) {
      const int clo = 2 * g, chi = 2 * g + 1;
      int x01 = pkbf(p[clo][0], p[clo][1]);
      int x23 = pkbf(p[clo][2], p[clo][3]);
      int y01 = pkbf(p[chi][0], p[chi][1]);
      int y23 = pkbf(p[chi][2], p[chi][3]);
      int xp01 = __shfl_xor(x01, 32, 64);
      int xp23 = __shfl_xor(x23, 32, 64);
      int yp01 = __shfl_xor(y01, 32, 64);
      int yp23 = __shfl_xor(y23, 32, 64);
      const bool lo = (l < 32);
      union { int d[4]; bf16x8 v; } pu;
      pu.d[0] = lo ? x01 : yp01;
      pu.d[1] = lo ? x23 : yp23;
      pu.d[2] = lo ? xp01 : y01;
      pu.d[3] = lo ? xp23 : y23;
#pragma unroll
      for (int dt = 0; dt < 4; ++dt) {
        bf16x8 va = *(const bf16x8*)(Vt + (16 * dt + lr) * 64 + (((4 * g + lg) ^ vsw) * 8));
        oacc[dt] = __builtin_amdgcn_mfma_f32_16x16x32_bf16(va, pu.v, oacc[dt], 0, 0, 0);
      }
    }
    __syncthreads();   // next tile staged (vmcnt drain) + all reads of cur done
  }

  // row sum: lanes l, l^16, l^32, l^48 share q-row lr
  lsum += __shfl_xor(lsum, 16, 64);
  lsum += __shfl_xor(lsum, 32, 64);
  const float inv = 1.f / lsum;
  const int b = bh / NH, h = bh % NH;
  const int q = q0 + w * 16 + lr;
  size_t obase = (size_t)(b * SEQ + q) * DIM + h * DH + 4 * lg;
#pragma unroll
  for (int dt = 0; dt < 4; ++dt) {
    ushort4 o;
    o.x = f2bf(oacc[dt][0] * inv);
    o.y = f2bf(oacc[dt][1] * inv);
    o.z = f2bf(oacc[dt][2] * inv);
    o.w = f2bf(oacc[dt][3] * inv);
    *(ushort4*)(Ob + obase + 16 * dt) = o;
  }
}

extern "C" void kernel_launch(void* const* d_in, const int* in_sizes, int n_in,
                              void* d_out, int out_size, void* d_ws, size_t ws_size,
                              hipStream_t stream) {
  const float* x      = (const float*)d_in[0];
  const float* pos    = (const float*)d_in[1];
  const float* qkv_w  = (const float*)d_in[2];
  const float* proj_w = (const float*)d_in[3];
  const float* proj_b = (const float*)d_in[4];
  const float* qn_w   = (const float*)d_in[5];
  const float* kn_w   = (const float*)d_in[6];
  char* ws = (char*)d_ws;
  u16*   xb    = (u16*)(ws + 0);          // 4096*768*2   = 6291456
  u16*   wqkv  = (u16*)(ws + 6291456);    // 2304*768*2   = 3538944
  u16*   wproj = (u16*)(ws + 9830400);    // 768*768*2    = 1179648
  u16*   qkvb  = (u16*)(ws + 11010048);   // 4096*2304*2  = 18874368
  u16*   Qb    = (u16*)(ws + 29884416);   // 6291456
  u16*   Kb    = (u16*)(ws + 36175872);   // 6291456
  u16*   Vtb   = (u16*)(ws + 42467328);   // 6291456
  u16*   Ob    = (u16*)(ws + 48758784);   // 6291456 -> total 55050240
  float* out = (float*)d_out;

  const int na4 = TOK * DIM / 4, nb4 = QKVN * DIM / 4, nc4 = DIM * DIM / 4;
  conv_all<<<(na4 + nb4 + nc4 + 255) / 256, 256, 0, stream>>>(
      x, xb, na4, qkv_w, wqkv, nb4, proj_w, wproj, nc4);

  dim3 g1(TOK / 128, QKVN / 128);
  gemm128<true><<<g1, 256, 0, stream>>>(xb, wqkv, qkvb, nullptr, TOK, QKVN, DIM);

  postproc<<<TOK, 256, 0, stream>>>(qkvb, pos, qn_w, kn_w, Qb, Kb, Vtb);

  attn<<<SEQ / 64 * BATCH * NH, 256, 0, stream>>>(Qb, Kb, Vtb, Ob);

  dim3 g3(TOK / 128, DIM / 128);
  gemm128<false><<<g3, 256, 0, stream>>>(Ob, wproj, out, proj_b, TOK, DIM, DIM);
}

// Round 5
// 134.587 us; speedup vs baseline: 2.6685x; 1.0365x over previous
//
#include <hip/hip_runtime.h>
#include <hip/hip_bf16.h>
#include <math.h>

#define DIM 768
#define NH 12
#define DH 64
#define SEQ 2048
#define BATCH 2
#define TOK (BATCH*SEQ)   // 4096
#define QKVN (3*DIM)      // 2304

typedef __attribute__((ext_vector_type(8))) short bf16x8;
typedef __attribute__((ext_vector_type(4))) float f32x4;
typedef __attribute__((ext_vector_type(2))) unsigned int u32x2;
typedef unsigned short u16;

__device__ inline u16 f2bf(float f) {
  union { float f; unsigned u; } v; v.f = f;
  unsigned u = v.u;
  u += 0x7fffu + ((u >> 16) & 1u);   // round-to-nearest-even
  return (u16)(u >> 16);
}

__device__ inline float bf2f(u16 h) {
  union { unsigned u; float f; } v; v.u = ((unsigned)h) << 16; return v.f;
}

__device__ inline int pkbf(float a, float b) {   // packed bf16 pair (RNE)
  __hip_bfloat162 h = __float22bfloat162_rn(make_float2(a, b));
  int r; __builtin_memcpy(&r, &h, 4); return r;
}

// One launch converts x, qkv_w, proj_w.
__global__ void conv_all(const float* __restrict__ a, u16* __restrict__ ao, int na4,
                         const float* __restrict__ b, u16* __restrict__ bo, int nb4,
                         const float* __restrict__ c, u16* __restrict__ co, int nc4) {
  int i4 = blockIdx.x * blockDim.x + threadIdx.x;
  const float* src; u16* dst; int off;
  if (i4 < na4)            { src = a; dst = ao; off = i4; }
  else if (i4 < na4 + nb4) { src = b; dst = bo; off = i4 - na4; }
  else if (i4 < na4 + nb4 + nc4) { src = c; dst = co; off = i4 - na4 - nb4; }
  else return;
  float4 v = ((const float4*)src)[off];
  ushort4 o;
  o.x = f2bf(v.x); o.y = f2bf(v.y); o.z = f2bf(v.z); o.w = f2bf(v.w);
  ((ushort4*)dst)[off] = o;
}

#define GLL(g, s) __builtin_amdgcn_global_load_lds((const __attribute__((address_space(1))) void*)(g), (__attribute__((address_space(3))) void*)(s), 16, 0, 0)

// C[M][Nn] = A[M][K] * W[Nn][K]^T (+bias), bf16 in, fp32 or bf16 out.
template<bool BF16OUT>
__global__ __launch_bounds__(256) void gemm128(
    const u16* __restrict__ A, const u16* __restrict__ W,
    void* __restrict__ Cv, const float* __restrict__ bias,
    int M, int Nn, int K)
{
  __shared__ u16 As[128 * 32];
  __shared__ u16 Bs[128 * 32];
  const int t = threadIdx.x;
  const int w = t >> 6, l = t & 63;
  const int lr = l & 15, lg = l >> 4;
  const int wr = w >> 1, wc = w & 1;
  const int m0 = blockIdx.x * 128;
  const int n0 = blockIdx.y * 128;
  f32x4 acc[4][4] = {};
  const int srow = t >> 2;
  const int scol = (t & 3) * 8;
  const u16* aSrc = A + (size_t)(m0 + srow) * K + scol;
  const u16* bSrc = W + (size_t)(n0 + srow) * K + scol;
  u16* aDst = As + w * 512;
  u16* bDst = Bs + w * 512;
  const size_t rstep = (size_t)64 * K;

  for (int k0 = 0; k0 < K; k0 += 32) {
    __syncthreads();
    GLL(aSrc + k0,          aDst);
    GLL(aSrc + rstep + k0,  aDst + 2048);
    GLL(bSrc + k0,          bDst);
    GLL(bSrc + rstep + k0,  bDst + 2048);
    __syncthreads();
    bf16x8 af[4], bff[4];
#pragma unroll
    for (int mi = 0; mi < 4; ++mi)
      af[mi] = *(const bf16x8*)(As + (wr * 64 + mi * 16 + lr) * 32 + lg * 8);
#pragma unroll
    for (int ni = 0; ni < 4; ++ni)
      bff[ni] = *(const bf16x8*)(Bs + (wc * 64 + ni * 16 + lr) * 32 + lg * 8);
#pragma unroll
    for (int mi = 0; mi < 4; ++mi)
#pragma unroll
      for (int ni = 0; ni < 4; ++ni)
        acc[mi][ni] = __builtin_amdgcn_mfma_f32_16x16x32_bf16(af[mi], bff[ni], acc[mi][ni], 0, 0, 0);
  }

#pragma unroll
  for (int mi = 0; mi < 4; ++mi) {
#pragma unroll
    for (int ni = 0; ni < 4; ++ni) {
#pragma unroll
      for (int r = 0; r < 4; ++r) {
        int row = m0 + wr * 64 + mi * 16 + lg * 4 + r;
        int col = n0 + wc * 64 + ni * 16 + lr;
        float v = acc[mi][ni][r];
        if constexpr (BF16OUT) {
          ((u16*)Cv)[(size_t)row * Nn + col] = f2bf(v);
        } else {
          if (bias) v += bias[col];
          ((float*)Cv)[(size_t)row * Nn + col] = v;
        }
      }
    }
  }
}

// RMSNorm(q,k) + RoPE from bf16 qkv. Q gets 0.125*log2(e) folded in.
__global__ __launch_bounds__(256) void postproc(
    const u16* __restrict__ qkv, const float* __restrict__ pos,
    const float* __restrict__ qn_w, const float* __restrict__ kn_w,
    u16* __restrict__ Qb, u16* __restrict__ Kb, u16* __restrict__ Vtb)
{
  const int t = blockIdx.x;
  const int w = threadIdx.x >> 6;
  const int d = threadIdx.x & 63;
  const int b = t >> 11, n = t & 2047;
  const float QSCALE = 0.125f * 1.4426950408889634f;
  float cs = 1.f, sn = 0.f;
  if (d < 60) {
    const int p = d >> 1;
    const int axis = p / 10, fi = p % 10;
    float freq = exp2f(-(float)fi * 1.3287712379549449f); // log2(10000)/10
    float ang = pos[t * 3 + axis] * freq;
    cs = cosf(ang); sn = sinf(ang);
  }
  const float qw = qn_w[d], kw = kn_w[d];
  for (int hh = 0; hh < 3; ++hh) {
    const int h = w + hh * 4;
    const u16* base = qkv + (size_t)t * QKVN + h * DH + d;
    float q = bf2f(base[0]), k = bf2f(base[DIM]), v = bf2f(base[2 * DIM]);
    float sq = q * q, sk = k * k;
#pragma unroll
    for (int off = 32; off >= 1; off >>= 1) {
      sq += __shfl_xor(sq, off, 64);
      sk += __shfl_xor(sk, off, 64);
    }
    float qn = q * rsqrtf(sq * (1.f / 64.f) + 1e-6f) * qw;
    float kn = k * rsqrtf(sk * (1.f / 64.f) + 1e-6f) * kw;
    float qo = __shfl_xor(qn, 1, 64);
    float ko = __shfl_xor(kn, 1, 64);
    float qr = qn, kr = kn;
    if (d < 60) {
      if (d & 1) { qr = qo * sn + qn * cs; kr = ko * sn + kn * cs; }
      else       { qr = qn * cs - qo * sn; kr = kn * cs - ko * sn; }
    }
    qr *= QSCALE;
    const size_t bh = (size_t)(b * NH + h);
    Qb[(bh * SEQ + n) * DH + d] = f2bf(qr);
    Kb[(bh * SEQ + n) * DH + d] = f2bf(kr);
    Vtb[(bh * DH + d) * SEQ + n] = f2bf(v);
  }
}

// Flash attention, swapped-operand, static-shift softmax (exact).
// 8 waves = 4 q-groups x 2 KV-halves. Waves (qg,0) compute even KV tiles,
// (qg,1) odd, from a pair-staged double buffer. Static shift => partial
// (oacc, lsum) are additive; halves combine via LDS scratch at the end.
// permlane32_swap builds the P^T B-frag in 2 VALU ops per dword-pair.
__global__ __launch_bounds__(512, 4) void attn(
    const u16* __restrict__ Qb, const u16* __restrict__ Kb,
    const u16* __restrict__ Vtb, u16* __restrict__ Ob)
{
  __shared__ u16 Ks[2][2][64 * 64];   // [pair dbuf][half] 8KB each
  __shared__ u16 Vs[2][2][64 * 64];
  const int tid = threadIdx.x;
  const int w = tid >> 6, l = tid & 63;
  const int lr = l & 15, lg = l >> 4;
  const int qg = w & 3, half = w >> 2;
  const int wg = blockIdx.x;
  const int swz = (wg & 7) * 96 + (wg >> 3);   // bijective, 768 % 8 == 0
  const int bh = swz >> 5;
  const int q0 = (swz & 31) * 64;
  const u16* Qp = Qb + (size_t)bh * SEQ * DH;
  const u16* Kp = Kb + (size_t)bh * SEQ * DH;
  const u16* Vp = Vtb + (size_t)bh * DH * SEQ;

  // Q B-frag: col = q = lr, k(d) = 8*lg+j.
  const int qrow = q0 + qg * 16 + lr;
  const bf16x8 bq0 = *(const bf16x8*)(Qp + (size_t)qrow * DH + 8 * lg);
  const bf16x8 bq1 = *(const bf16x8*)(Qp + (size_t)qrow * DH + 32 + 8 * lg);

  // staging: 512 threads cover one 8KB tile; chunk c=tid: row c>>3, col16 (c&7)^(row&7)
  const int srow = tid >> 3;
  const int sc16 = (tid & 7) ^ (srow & 7);
  const u16* kSrc = Kp + (size_t)srow * DH + sc16 * 8;    // + kt*4096
  const u16* vSrc = Vp + (size_t)srow * SEQ + sc16 * 8;   // + kt*64

  // K A-frag read constants: row = 16c + frow (bit2<->3 swap of lr)
  const int frow = (lr & 3) | ((lr & 4) << 1) | ((lr & 8) >> 1);
  const int ksw = frow & 7;
  const int vsw = lr & 7;

  f32x4 oacc[4] = {};
  float lsum = 0.f;

  // prologue: stage tiles 0,1 into pair-buffer 0
  GLL(kSrc,        &Ks[0][0][w * 512]);
  GLL(kSrc + 4096, &Ks[0][1][w * 512]);
  GLL(vSrc,        &Vs[0][0][w * 512]);
  GLL(vSrc + 64,   &Vs[0][1][w * 512]);
  __syncthreads();

  for (int i = 0; i < 16; ++i) {
    const int p = i & 1;
    if (i + 1 < 16) {
      const size_t ko = (size_t)(2 * i + 2) * 4096;
      const size_t vo = (size_t)(2 * i + 2) * 64;
      GLL(kSrc + ko,        &Ks[p ^ 1][0][w * 512]);
      GLL(kSrc + ko + 4096, &Ks[p ^ 1][1][w * 512]);
      GLL(vSrc + vo,        &Vs[p ^ 1][0][w * 512]);
      GLL(vSrc + vo + 64,   &Vs[p ^ 1][1][w * 512]);
    }
    const u16* Kt = &Ks[p][half][0];
    const u16* Vt = &Vs[p][half][0];

    // S^T tiles: pacc[c] cols=q(lr), rows=kk(4lg+r) -> physical k=16c+f(4lg+r)
    f32x4 pacc[4] = {};
    __builtin_amdgcn_s_setprio(1);
#pragma unroll
    for (int c = 0; c < 4; ++c) {
      const int rbase = (16 * c + frow) * 64;
      bf16x8 ka = *(const bf16x8*)(Kt + rbase + ((lg ^ ksw) * 8));
      bf16x8 kb = *(const bf16x8*)(Kt + rbase + (((4 + lg) ^ ksw) * 8));
      pacc[c] = __builtin_amdgcn_mfma_f32_16x16x32_bf16(ka, bq0, pacc[c], 0, 0, 0);
      pacc[c] = __builtin_amdgcn_mfma_f32_16x16x32_bf16(kb, bq1, pacc[c], 0, 0, 0);
    }
    __builtin_amdgcn_s_setprio(0);
    // p = 2^(s' - 12), exact softmax shift (|S'| <= 11.54)
    float pp[4][4];
#pragma unroll
    for (int c = 0; c < 4; ++c)
#pragma unroll
      for (int r = 0; r < 4; ++r) {
        float pv = __builtin_amdgcn_exp2f(pacc[c][r] - 12.f);
        pp[c][r] = pv;
        lsum += pv;
      }
    // Build P^T B-frags via permlane32_swap and accumulate O^T = mfma(Vt, P^T)
#pragma unroll
    for (int g = 0; g < 2; ++g) {
      const int clo = 2 * g, chi = 2 * g + 1;
      unsigned x01 = (unsigned)pkbf(pp[clo][0], pp[clo][1]);
      unsigned x23 = (unsigned)pkbf(pp[clo][2], pp[clo][3]);
      unsigned y01 = (unsigned)pkbf(pp[chi][0], pp[chi][1]);
      unsigned y23 = (unsigned)pkbf(pp[chi][2], pp[chi][3]);
      u32x2 r0 = __builtin_amdgcn_permlane32_swap(x01, y01, false, false); // d0,d2
      u32x2 r1 = __builtin_amdgcn_permlane32_swap(x23, y23, false, false); // d1,d3
      union { unsigned d[4]; bf16x8 v; } pu;
      pu.d[0] = r0[0]; pu.d[1] = r1[0]; pu.d[2] = r0[1]; pu.d[3] = r1[1];
      __builtin_amdgcn_s_setprio(1);
#pragma unroll
      for (int dt = 0; dt < 4; ++dt) {
        bf16x8 va = *(const bf16x8*)(Vt + (16 * dt + lr) * 64 + (((4 * g + lg) ^ vsw) * 8));
        oacc[dt] = __builtin_amdgcn_mfma_f32_16x16x32_bf16(va, pu.v, oacc[dt], 0, 0, 0);
      }
      __builtin_amdgcn_s_setprio(0);
    }
    __syncthreads();   // pair i+1 staged; all reads of pair i done
  }

  // combine halves: static shift => partials additive. half=1 -> LDS scratch.
  float* scr = (float*)&Ks[0][0][0];   // safe to reuse after final barrier
  const int sid = qg * 64 + l;
  if (half == 1) {
#pragma unroll
    for (int dt = 0; dt < 4; ++dt)
#pragma unroll
      for (int r = 0; r < 4; ++r)
        scr[sid * 17 + dt * 4 + r] = oacc[dt][r];
    scr[sid * 17 + 16] = lsum;
  }
  __syncthreads();
  if (half == 1) return;
#pragma unroll
  for (int dt = 0; dt < 4; ++dt)
#pragma unroll
    for (int r = 0; r < 4; ++r)
      oacc[dt][r] += scr[sid * 17 + dt * 4 + r];
  lsum += scr[sid * 17 + 16];

  // row sum: lanes l, l^16, l^32, l^48 share q-row lr
  lsum += __shfl_xor(lsum, 16, 64);
  lsum += __shfl_xor(lsum, 32, 64);
  const float inv = 1.f / lsum;
  const int b = bh / NH, h = bh % NH;
  const int q = q0 + qg * 16 + lr;
  size_t obase = (size_t)(b * SEQ + q) * DIM + h * DH + 4 * lg;
#pragma unroll
  for (int dt = 0; dt < 4; ++dt) {
    ushort4 o;
    o.x = f2bf(oacc[dt][0] * inv);
    o.y = f2bf(oacc[dt][1] * inv);
    o.z = f2bf(oacc[dt][2] * inv);
    o.w = f2bf(oacc[dt][3] * inv);
    *(ushort4*)(Ob + obase + 16 * dt) = o;
  }
}

extern "C" void kernel_launch(void* const* d_in, const int* in_sizes, int n_in,
                              void* d_out, int out_size, void* d_ws, size_t ws_size,
                              hipStream_t stream) {
  const float* x      = (const float*)d_in[0];
  const float* pos    = (const float*)d_in[1];
  const float* qkv_w  = (const float*)d_in[2];
  const float* proj_w = (const float*)d_in[3];
  const float* proj_b = (const float*)d_in[4];
  const float* qn_w   = (const float*)d_in[5];
  const float* kn_w   = (const float*)d_in[6];
  char* ws = (char*)d_ws;
  u16*   xb    = (u16*)(ws + 0);          // 4096*768*2   = 6291456
  u16*   wqkv  = (u16*)(ws + 6291456);    // 2304*768*2   = 3538944
  u16*   wproj = (u16*)(ws + 9830400);    // 768*768*2    = 1179648
  u16*   qkvb  = (u16*)(ws + 11010048);   // 4096*2304*2  = 18874368
  u16*   Qb    = (u16*)(ws + 29884416);   // 6291456
  u16*   Kb    = (u16*)(ws + 36175872);   // 6291456
  u16*   Vtb   = (u16*)(ws + 42467328);   // 6291456
  u16*   Ob    = (u16*)(ws + 48758784);   // 6291456 -> total 55050240
  float* out = (float*)d_out;

  const int na4 = TOK * DIM / 4, nb4 = QKVN * DIM / 4, nc4 = DIM * DIM / 4;
  conv_all<<<(na4 + nb4 + nc4 + 255) / 256, 256, 0, stream>>>(
      x, xb, na4, qkv_w, wqkv, nb4, proj_w, wproj, nc4);

  dim3 g1(TOK / 128, QKVN / 128);
  gemm128<true><<<g1, 256, 0, stream>>>(xb, wqkv, qkvb, nullptr, TOK, QKVN, DIM);

  postproc<<<TOK, 256, 0, stream>>>(qkvb, pos, qn_w, kn_w, Qb, Kb, Vtb);

  attn<<<SEQ / 64 * BATCH * NH, 512, 0, stream>>>(Qb, Kb, Vtb, Ob);

  dim3 g3(TOK / 128, DIM / 128);
  gemm128<false><<<g3, 256, 0, stream>>>(Ob, wproj, out, proj_b, TOK, DIM, DIM);
}

// Round 6
// 111.129 us; speedup vs baseline: 3.2317x; 1.2111x over previous
//
#include <hip/hip_runtime.h>
#include <hip/hip_bf16.h>
#include <math.h>

#define DIM 768
#define NH 12
#define DH 64
#define SEQ 2048
#define BATCH 2
#define TOK (BATCH*SEQ)   // 4096
#define QKVN (3*DIM)      // 2304

typedef __attribute__((ext_vector_type(8))) short bf16x8;
typedef __attribute__((ext_vector_type(4))) float f32x4;
typedef __attribute__((ext_vector_type(2))) unsigned int u32x2;
typedef unsigned short u16;

__device__ inline u16 f2bf(float f) {
  union { float f; unsigned u; } v; v.f = f;
  unsigned u = v.u;
  u += 0x7fffu + ((u >> 16) & 1u);   // round-to-nearest-even
  return (u16)(u >> 16);
}

__device__ inline int pkbf(float a, float b) {   // packed bf16 pair (RNE)
  __hip_bfloat162 h = __float22bfloat162_rn(make_float2(a, b));
  int r; __builtin_memcpy(&r, &h, 4); return r;
}

// One launch converts x, qkv_w, proj_w.
__global__ void conv_all(const float* __restrict__ a, u16* __restrict__ ao, int na4,
                         const float* __restrict__ b, u16* __restrict__ bo, int nb4,
                         const float* __restrict__ c, u16* __restrict__ co, int nc4) {
  int i4 = blockIdx.x * blockDim.x + threadIdx.x;
  const float* src; u16* dst; int off;
  if (i4 < na4)            { src = a; dst = ao; off = i4; }
  else if (i4 < na4 + nb4) { src = b; dst = bo; off = i4 - na4; }
  else if (i4 < na4 + nb4 + nc4) { src = c; dst = co; off = i4 - na4 - nb4; }
  else return;
  float4 v = ((const float4*)src)[off];
  ushort4 o;
  o.x = f2bf(v.x); o.y = f2bf(v.y); o.z = f2bf(v.z); o.w = f2bf(v.w);
  ((ushort4*)dst)[off] = o;
}

// cos/sin table: tab[t*32+p], p<30 real, p>=30 -> (1,0) passthrough.
__global__ void rope_tab(const float* __restrict__ pos, float2* __restrict__ tab) {
  int e = blockIdx.x * blockDim.x + threadIdx.x;   // 4096*32
  int t = e >> 5, p = e & 31;
  float cs = 1.f, sn = 0.f;
  if (p < 30) {
    int axis = p / 10, fi = p % 10;
    float freq = exp2f(-(float)fi * 1.3287712379549449f); // log2(10000)/10
    float ang = pos[t * 3 + axis] * freq;
    cs = cosf(ang); sn = sinf(ang);
  }
  tab[e] = make_float2(cs, sn);
}

#define GLL(g, s) __builtin_amdgcn_global_load_lds((const __attribute__((address_space(1))) void*)(g), (__attribute__((address_space(3))) void*)(s), 16, 0, 0)

// Proj GEMM: C[M][Nn] = A[M][K] * W[Nn][K]^T + bias, bf16 in, fp32 out.
__global__ __launch_bounds__(256) void gemm128(
    const u16* __restrict__ A, const u16* __restrict__ W,
    float* __restrict__ C, const float* __restrict__ bias,
    int M, int Nn, int K)
{
  __shared__ u16 As[128 * 32];
  __shared__ u16 Bs[128 * 32];
  const int t = threadIdx.x;
  const int w = t >> 6, l = t & 63;
  const int lr = l & 15, lg = l >> 4;
  const int wr = w >> 1, wc = w & 1;
  const int m0 = blockIdx.x * 128;
  const int n0 = blockIdx.y * 128;
  f32x4 acc[4][4] = {};
  const int srow = t >> 2;
  const int scol = (t & 3) * 8;
  const u16* aSrc = A + (size_t)(m0 + srow) * K + scol;
  const u16* bSrc = W + (size_t)(n0 + srow) * K + scol;
  u16* aDst = As + w * 512;
  u16* bDst = Bs + w * 512;
  const size_t rstep = (size_t)64 * K;

  for (int k0 = 0; k0 < K; k0 += 32) {
    __syncthreads();
    GLL(aSrc + k0,          aDst);
    GLL(aSrc + rstep + k0,  aDst + 2048);
    GLL(bSrc + k0,          bDst);
    GLL(bSrc + rstep + k0,  bDst + 2048);
    __syncthreads();
    bf16x8 af[4], bff[4];
#pragma unroll
    for (int mi = 0; mi < 4; ++mi)
      af[mi] = *(const bf16x8*)(As + (wr * 64 + mi * 16 + lr) * 32 + lg * 8);
#pragma unroll
    for (int ni = 0; ni < 4; ++ni)
      bff[ni] = *(const bf16x8*)(Bs + (wc * 64 + ni * 16 + lr) * 32 + lg * 8);
#pragma unroll
    for (int mi = 0; mi < 4; ++mi)
#pragma unroll
      for (int ni = 0; ni < 4; ++ni)
        acc[mi][ni] = __builtin_amdgcn_mfma_f32_16x16x32_bf16(af[mi], bff[ni], acc[mi][ni], 0, 0, 0);
  }

#pragma unroll
  for (int mi = 0; mi < 4; ++mi)
#pragma unroll
    for (int ni = 0; ni < 4; ++ni)
#pragma unroll
      for (int r = 0; r < 4; ++r) {
        int row = m0 + wr * 64 + mi * 16 + lg * 4 + r;
        int col = n0 + wc * 64 + ni * 16 + lr;
        C[(size_t)row * Nn + col] = acc[mi][ni][r] + bias[col];
      }
}

// QKV GEMM with fused RMSNorm + RoPE + layout epilogue.
// Each wave's 64-col span = one (type,head) chunk. Writes Qb (scaled, roped),
// Kb (roped), Vtb (transposed) bf16 directly.
__global__ __launch_bounds__(256) void gemm_qkv(
    const u16* __restrict__ A, const u16* __restrict__ W,
    const float* __restrict__ qn_w, const float* __restrict__ kn_w,
    const float2* __restrict__ tab,
    u16* __restrict__ Qb, u16* __restrict__ Kb, u16* __restrict__ Vtb)
{
  __shared__ u16 As[128 * 32];
  __shared__ u16 Bs[128 * 32];
  const int K = DIM;
  const int t = threadIdx.x;
  const int w = t >> 6, l = t & 63;
  const int lr = l & 15, lg = l >> 4;
  const int wr = w >> 1, wc = w & 1;
  const int m0 = blockIdx.x * 128;
  const int n0 = blockIdx.y * 128;
  f32x4 acc[4][4] = {};
  const int srow = t >> 2;
  const int scol = (t & 3) * 8;
  const u16* aSrc = A + (size_t)(m0 + srow) * K + scol;
  const u16* bSrc = W + (size_t)(n0 + srow) * K + scol;
  u16* aDst = As + w * 512;
  u16* bDst = Bs + w * 512;
  const size_t rstep = (size_t)64 * K;

  for (int k0 = 0; k0 < K; k0 += 32) {
    __syncthreads();
    GLL(aSrc + k0,          aDst);
    GLL(aSrc + rstep + k0,  aDst + 2048);
    GLL(bSrc + k0,          bDst);
    GLL(bSrc + rstep + k0,  bDst + 2048);
    __syncthreads();
    bf16x8 af[4], bff[4];
#pragma unroll
    for (int mi = 0; mi < 4; ++mi)
      af[mi] = *(const bf16x8*)(As + (wr * 64 + mi * 16 + lr) * 32 + lg * 8);
#pragma unroll
    for (int ni = 0; ni < 4; ++ni)
      bff[ni] = *(const bf16x8*)(Bs + (wc * 64 + ni * 16 + lr) * 32 + lg * 8);
#pragma unroll
    for (int mi = 0; mi < 4; ++mi)
#pragma unroll
      for (int ni = 0; ni < 4; ++ni)
        acc[mi][ni] = __builtin_amdgcn_mfma_f32_16x16x32_bf16(af[mi], bff[ni], acc[mi][ni], 0, 0, 0);
  }

  // ---- fused epilogue ----
  const int chunk = (n0 >> 6) + wc;        // 0..35 over [3 types][12 heads]
  const int tt = chunk / 12;               // 0=q 1=k 2=v
  const int h  = chunk % 12;
  const int bB = m0 >> 11;                 // batch (128 | 2048 => block-const)
  const int bh = bB * NH + h;

  if (tt == 2) {
    // V: transposed (B,H,DH,N)
#pragma unroll
    for (int mi = 0; mi < 4; ++mi) {
      const int nbase = (m0 + wr * 64 + mi * 16 + lg * 4) & 2047;
#pragma unroll
      for (int ni = 0; ni < 4; ++ni) {
        const int d = ni * 16 + lr;
        ushort4 o;
        o.x = f2bf(acc[mi][ni][0]); o.y = f2bf(acc[mi][ni][1]);
        o.z = f2bf(acc[mi][ni][2]); o.w = f2bf(acc[mi][ni][3]);
        *(ushort4*)(Vtb + ((size_t)bh * DH + d) * SEQ + nbase) = o;
      }
    }
  } else {
    const float* wv = (tt == 0 ? qn_w : kn_w);
    const float qs = (tt == 0 ? 0.125f * 1.4426950408889634f : 1.f);
    float wgt[4];
#pragma unroll
    for (int ni = 0; ni < 4; ++ni) wgt[ni] = wv[ni * 16 + lr];
    u16* outp = (tt == 0 ? Qb : Kb) + (size_t)bh * SEQ * DH;
#pragma unroll
    for (int mi = 0; mi < 4; ++mi) {
#pragma unroll
      for (int r = 0; r < 4; ++r) {
        float ss = 0.f;
#pragma unroll
        for (int ni = 0; ni < 4; ++ni) ss += acc[mi][ni][r] * acc[mi][ni][r];
        ss += __shfl_xor(ss, 1, 64);
        ss += __shfl_xor(ss, 2, 64);
        ss += __shfl_xor(ss, 4, 64);
        ss += __shfl_xor(ss, 8, 64);
        const float rms = rsqrtf(ss * (1.f / 64.f) + 1e-6f);
        const int trow = m0 + wr * 64 + mi * 16 + lg * 4 + r;
        const float2* tl = tab + trow * 32;
        u16* rowp = outp + (size_t)(trow & 2047) * DH;
#pragma unroll
        for (int ni = 0; ni < 4; ++ni) {
          const int d = ni * 16 + lr;
          float v = acc[mi][ni][r] * rms * wgt[ni];
          float vp = __shfl_xor(v, 1, 64);
          float2 cssn = tl[ni * 8 + (lr >> 1)];
          float sgn = (d & 1) ? cssn.y : -cssn.y;
          rowp[d] = f2bf((v * cssn.x + vp * sgn) * qs);
        }
      }
    }
  }
}

// Flash attention, swapped-operand, static-shift softmax (exact).
// 8 waves = 4 q-groups x 2 KV-halves. K pair-dbuf (32KB) + single V pair
// buffer (16KB) => 48KB LDS => 3 blocks/CU, all 768 blocks resident.
// Two barriers/step: alpha (V ready, after QK/softmax) and beta (V free).
__global__ __launch_bounds__(512, 6) void attn(
    const u16* __restrict__ Qb, const u16* __restrict__ Kb,
    const u16* __restrict__ Vtb, u16* __restrict__ Ob)
{
  __shared__ u16 Ks[2][2][64 * 64];   // [pair dbuf][half]
  __shared__ u16 Vs[2][64 * 64];      // [half] single pair buffer
  const int tid = threadIdx.x;
  const int w = tid >> 6, l = tid & 63;
  const int lr = l & 15, lg = l >> 4;
  const int qg = w & 3, half = w >> 2;
  const int wg = blockIdx.x;
  const int swz = (wg & 7) * 96 + (wg >> 3);   // bijective, 768 % 8 == 0
  const int bh = swz >> 5;
  const int q0 = (swz & 31) * 64;
  const u16* Qp = Qb + (size_t)bh * SEQ * DH;
  const u16* Kp = Kb + (size_t)bh * SEQ * DH;
  const u16* Vp = Vtb + (size_t)bh * DH * SEQ;

  const int qrow = q0 + qg * 16 + lr;
  const bf16x8 bq0 = *(const bf16x8*)(Qp + (size_t)qrow * DH + 8 * lg);
  const bf16x8 bq1 = *(const bf16x8*)(Qp + (size_t)qrow * DH + 32 + 8 * lg);

  // staging: 512 threads cover one 8KB tile; chunk tid: row tid>>3, col16 (tid&7)^(row&7)
  const int srow = tid >> 3;
  const int sc16 = (tid & 7) ^ (srow & 7);
  const u16* kSrc = Kp + (size_t)srow * DH + sc16 * 8;    // + kt*4096
  const u16* vSrc = Vp + (size_t)srow * SEQ + sc16 * 8;   // + kt*64

  const int frow = (lr & 3) | ((lr & 4) << 1) | ((lr & 8) >> 1);
  const int ksw = frow & 7;
  const int vsw = lr & 7;

  f32x4 oacc[4] = {};
  float lsum = 0.f;

  // prologue: stage pair 0 (K -> Ks[0], V -> Vs)
  GLL(kSrc,        &Ks[0][0][w * 512]);
  GLL(kSrc + 4096, &Ks[0][1][w * 512]);
  GLL(vSrc,        &Vs[0][w * 512]);
  GLL(vSrc + 64,   &Vs[1][w * 512]);
  __syncthreads();

  for (int i = 0; i < 16; ++i) {
    const int p = i & 1;
    if (i + 1 < 16) {   // K prefetch for pair i+1 (flies over QK+softmax)
      const size_t ko = (size_t)(2 * i + 2) * 4096;
      GLL(kSrc + ko,        &Ks[p ^ 1][0][w * 512]);
      GLL(kSrc + ko + 4096, &Ks[p ^ 1][1][w * 512]);
    }
    const u16* Kt = &Ks[p][half][0];
    const u16* Vt = &Vs[half][0];

    // QK: S^T tiles
    f32x4 pacc[4] = {};
    __builtin_amdgcn_s_setprio(1);
#pragma unroll
    for (int c = 0; c < 4; ++c) {
      const int rbase = (16 * c + frow) * 64;
      bf16x8 ka = *(const bf16x8*)(Kt + rbase + ((lg ^ ksw) * 8));
      bf16x8 kb = *(const bf16x8*)(Kt + rbase + (((4 + lg) ^ ksw) * 8));
      pacc[c] = __builtin_amdgcn_mfma_f32_16x16x32_bf16(ka, bq0, pacc[c], 0, 0, 0);
      pacc[c] = __builtin_amdgcn_mfma_f32_16x16x32_bf16(kb, bq1, pacc[c], 0, 0, 0);
    }
    __builtin_amdgcn_s_setprio(0);
    float pp[4][4];
#pragma unroll
    for (int c = 0; c < 4; ++c)
#pragma unroll
      for (int r = 0; r < 4; ++r) {
        float pv = __builtin_amdgcn_exp2f(pacc[c][r] - 12.f);
        pp[c][r] = pv;
        lsum += pv;
      }

    __syncthreads();   // alpha: V(i) GLLs (issued end of iter i-1) drained

    // PV from Vs[half]
#pragma unroll
    for (int g = 0; g < 2; ++g) {
      const int clo = 2 * g, chi = 2 * g + 1;
      unsigned x01 = (unsigned)pkbf(pp[clo][0], pp[clo][1]);
      unsigned x23 = (unsigned)pkbf(pp[clo][2], pp[clo][3]);
      unsigned y01 = (unsigned)pkbf(pp[chi][0], pp[chi][1]);
      unsigned y23 = (unsigned)pkbf(pp[chi][2], pp[chi][3]);
      u32x2 r0 = __builtin_amdgcn_permlane32_swap(x01, y01, false, false);
      u32x2 r1 = __builtin_amdgcn_permlane32_swap(x23, y23, false, false);
      union { unsigned d[4]; bf16x8 v; } pu;
      pu.d[0] = r0[0]; pu.d[1] = r1[0]; pu.d[2] = r0[1]; pu.d[3] = r1[1];
      __builtin_amdgcn_s_setprio(1);
#pragma unroll
      for (int dt = 0; dt < 4; ++dt) {
        bf16x8 va = *(const bf16x8*)(Vt + (16 * dt + lr) * 64 + (((4 * g + lg) ^ vsw) * 8));
        oacc[dt] = __builtin_amdgcn_mfma_f32_16x16x32_bf16(va, pu.v, oacc[dt], 0, 0, 0);
      }
      __builtin_amdgcn_s_setprio(0);
    }

    __syncthreads();   // beta: all waves done reading Vs (no outstanding GLLs)

    if (i + 1 < 16) {  // V stage for pair i+1 (flies over next QK+softmax)
      const size_t vo = (size_t)(2 * i + 2) * 64;
      GLL(vSrc + vo,      &Vs[0][w * 512]);
      GLL(vSrc + vo + 64, &Vs[1][w * 512]);
    }
  }

  // combine halves (static shift => additive partials)
  float* scr = (float*)&Ks[0][0][0];
  const int sid = qg * 64 + l;
  if (half == 1) {
#pragma unroll
    for (int dt = 0; dt < 4; ++dt)
#pragma unroll
      for (int r = 0; r < 4; ++r)
        scr[sid * 17 + dt * 4 + r] = oacc[dt][r];
    scr[sid * 17 + 16] = lsum;
  }
  __syncthreads();
  if (half == 1) return;
#pragma unroll
  for (int dt = 0; dt < 4; ++dt)
#pragma unroll
    for (int r = 0; r < 4; ++r)
      oacc[dt][r] += scr[sid * 17 + dt * 4 + r];
  lsum += scr[sid * 17 + 16];

  lsum += __shfl_xor(lsum, 16, 64);
  lsum += __shfl_xor(lsum, 32, 64);
  const float inv = 1.f / lsum;
  const int b = bh / NH, h = bh % NH;
  const int q = q0 + qg * 16 + lr;
  size_t obase = (size_t)(b * SEQ + q) * DIM + h * DH + 4 * lg;
#pragma unroll
  for (int dt = 0; dt < 4; ++dt) {
    ushort4 o;
    o.x = f2bf(oacc[dt][0] * inv);
    o.y = f2bf(oacc[dt][1] * inv);
    o.z = f2bf(oacc[dt][2] * inv);
    o.w = f2bf(oacc[dt][3] * inv);
    *(ushort4*)(Ob + obase + 16 * dt) = o;
  }
}

extern "C" void kernel_launch(void* const* d_in, const int* in_sizes, int n_in,
                              void* d_out, int out_size, void* d_ws, size_t ws_size,
                              hipStream_t stream) {
  const float* x      = (const float*)d_in[0];
  const float* pos    = (const float*)d_in[1];
  const float* qkv_w  = (const float*)d_in[2];
  const float* proj_w = (const float*)d_in[3];
  const float* proj_b = (const float*)d_in[4];
  const float* qn_w   = (const float*)d_in[5];
  const float* kn_w   = (const float*)d_in[6];
  char* ws = (char*)d_ws;
  u16*    xb    = (u16*)(ws + 0);          // 6291456
  u16*    wqkv  = (u16*)(ws + 6291456);    // 3538944
  u16*    wproj = (u16*)(ws + 9830400);    // 1179648
  float2* tab   = (float2*)(ws + 11010048);// 4096*32*8 = 1048576
  u16*    Qb    = (u16*)(ws + 12058624);   // 6291456
  u16*    Kb    = (u16*)(ws + 18350080);   // 6291456
  u16*    Vtb   = (u16*)(ws + 24641536);   // 6291456
  u16*    Ob    = (u16*)(ws + 30932992);   // 6291456 -> total 37224448
  float* out = (float*)d_out;

  const int na4 = TOK * DIM / 4, nb4 = QKVN * DIM / 4, nc4 = DIM * DIM / 4;
  conv_all<<<(na4 + nb4 + nc4 + 255) / 256, 256, 0, stream>>>(
      x, xb, na4, qkv_w, wqkv, nb4, proj_w, wproj, nc4);

  rope_tab<<<TOK * 32 / 256, 256, 0, stream>>>(pos, tab);

  dim3 g1(TOK / 128, QKVN / 128);
  gemm_qkv<<<g1, 256, 0, stream>>>(xb, wqkv, qn_w, kn_w, tab, Qb, Kb, Vtb);

  attn<<<SEQ / 64 * BATCH * NH, 512, 0, stream>>>(Qb, Kb, Vtb, Ob);

  dim3 g3(TOK / 128, DIM / 128);
  gemm128<<<g3, 256, 0, stream>>>(Ob, wproj, out, proj_b, TOK, DIM, DIM);
}